// Round 3
// baseline (582.573 us; speedup 1.0000x reference)
//
#include <hip/hip_runtime.h>
#include <cstdint>

#define CC 32
#define DD 9
#define CD 288   // C*D
#define BB 8
#define HH 64
#define ZZ 4

__device__ __forceinline__ float silu_f(float v) {
  return v / (1.0f + __expf(-v));
}

__device__ __forceinline__ int blk_of(int d) { return d == 0 ? 0 : (d < 4 ? 1 : 2); }

__global__ __launch_bounds__(256) void k_zero(float* __restrict__ p, int n) {
  int i = blockIdx.x * 256 + threadIdx.x;
  if (i < n) p[i] = 0.0f;
}

// ---------------- CSR build ----------------
__global__ __launch_bounds__(256) void k_hist(const int* __restrict__ edst,
                                              int* __restrict__ deg, int E) {
  int e = blockIdx.x * 256 + threadIdx.x;
  if (e < E) atomicAdd(&deg[edst[e]], 1);
}

// single block of 1024; exclusive scan of deg[N] -> offs[N+1], cursor
__global__ __launch_bounds__(1024) void k_scan(const int* __restrict__ deg,
                                               int* __restrict__ offs,
                                               int* __restrict__ cursor, int N) {
  __shared__ int part[1024];
  int t = threadIdx.x;
  int chunk = (N + 1023) >> 10;
  int base = t * chunk;
  int lim = N - base; if (lim > chunk) lim = chunk; if (lim < 0) lim = 0;
  int s = 0;
  for (int i = 0; i < lim; ++i) s += deg[base + i];
  part[t] = s;
  __syncthreads();
  for (int off = 1; off < 1024; off <<= 1) {
    int v = part[t];
    int u = (t >= off) ? part[t - off] : 0;
    __syncthreads();
    part[t] = v + u;
    __syncthreads();
  }
  int run = (t == 0) ? 0 : part[t - 1];
  for (int i = 0; i < lim; ++i) {
    offs[base + i] = run;
    cursor[base + i] = run;
    run += deg[base + i];
  }
  if (t == 1023) offs[N] = run;
}

__global__ __launch_bounds__(256) void k_scatter(const int* __restrict__ edst,
                                                 int* __restrict__ cursor,
                                                 int* __restrict__ eidx, int E) {
  int e = blockIdx.x * 256 + threadIdx.x;
  if (e < E) {
    int d = edst[e];
    int pos = atomicAdd(&cursor[d], 1);
    eidx[pos] = e;
  }
}

// ---------------- linear_up: x[n][d][q] = sum_c nf[n][c][d]*Wup[l(d)][c][q] ----------------
__global__ __launch_bounds__(256) void k_linear_up(
    const float* __restrict__ nf, const float* __restrict__ Wup,
    float* __restrict__ x, int N) {
  __shared__ float sW[3 * CC * CC];
  __shared__ float snf[8 * CD];
  for (int i = threadIdx.x; i < 3 * CC * CC; i += 256) sW[i] = Wup[i];
  int node0 = blockIdx.x * 8;
  int cnt = N - node0; if (cnt > 8) cnt = 8;
  const float* src = nf + (size_t)node0 * CD;
  for (int i = threadIdx.x; i < cnt * CD; i += 256) snf[i] = src[i];
  __syncthreads();
  float* dst = x + (size_t)node0 * CD;
  for (int o = threadIdx.x; o < cnt * CD; o += 256) {
    int nl = o / CD, rem = o - nl * CD;
    int d = rem >> 5, q = rem & 31;
    int l = blk_of(d);
    const float* wcol = sW + l * (CC * CC) + q;
    const float* frow = snf + nl * CD + d;
    float acc = 0.f;
#pragma unroll
    for (int c = 0; c < CC; ++c) acc += frow[c * DD] * wcol[c * CC];
    dst[o] = acc;
  }
}

// ---------------- radial MLP: one lane = one edge; weights via uniform s_load ----------------
__global__ __launch_bounds__(256) void k_mlp(
    const float* __restrict__ ef, const float* __restrict__ cut,
    const float* __restrict__ W1, const float* __restrict__ W2,
    const float* __restrict__ W3, float* __restrict__ w, int E) {
  int e = blockIdx.x * 256 + threadIdx.x;
  if (e >= E) return;
  const float4* efp = (const float4*)(ef + (size_t)e * BB);
  float4 efa = efp[0];
  float4 efb = efp[1];
  float efv[BB] = {efa.x, efa.y, efa.z, efa.w, efb.x, efb.y, efb.z, efb.w};
  float h1[HH];
#pragma unroll 16
  for (int q = 0; q < HH; ++q) {
    float acc = 0.f;
#pragma unroll
    for (int k = 0; k < BB; ++k) acc += efv[k] * W1[k * HH + q];
    h1[q] = silu_f(acc);
  }
  float wacc[CC];
#pragma unroll
  for (int c = 0; c < CC; ++c) wacc[c] = 0.f;
#pragma unroll 8
  for (int q = 0; q < HH; ++q) {
    float acc = 0.f;
#pragma unroll
    for (int k = 0; k < HH; ++k) acc += h1[k] * W2[k * HH + q];
    float h2 = silu_f(acc);
#pragma unroll
    for (int c = 0; c < CC; ++c) wacc[c] += h2 * W3[q * CC + c];
  }
  float cv = cut[e];
  float4* wp = (float4*)(w + (size_t)e * CC);
#pragma unroll
  for (int i = 0; i < 8; ++i) {
    float4 v;
    v.x = wacc[i * 4 + 0] * cv;
    v.y = wacc[i * 4 + 1] * cv;
    v.z = wacc[i * 4 + 2] * cv;
    v.w = wacc[i * 4 + 3] * cv;
    wp[i] = v;
  }
}

// ---------------- gather: one wave per node, halves split even/odd edges ----------------
// P[c][i][j] = sum_e (w_ec * x[src_e][i][c]) * sh_e[j];  m[c][k] = sum_ij P*CG[i][j][k]
__global__ __launch_bounds__(256) void k_gather(
    const float* __restrict__ x, const float* __restrict__ w,
    const float* __restrict__ esh, const float* __restrict__ CG,
    const int* __restrict__ offs, const int* __restrict__ eidx,
    const int* __restrict__ esrc, float* __restrict__ mpre, int N) {
  int wid = (blockIdx.x * 256 + threadIdx.x) >> 6;  // node id
  if (wid >= N) return;
  int lane = threadIdx.x & 63;
  int h = lane >> 5, c = lane & 31;
  int beg = offs[wid], end = offs[wid + 1];
  float P[81];
#pragma unroll
  for (int i = 0; i < 81; ++i) P[i] = 0.f;
  for (int p0 = beg; p0 < end; p0 += 2) {
    int p = p0 + h;
    bool ok = p < end;
    int pp = ok ? p : p0;
    int e = eidx[pp];
    int s = esrc[e];
    float wc = ok ? w[(size_t)e * CC + c] : 0.f;
    const float* shp = esh + (size_t)e * DD;
    float sh[DD];
#pragma unroll
    for (int j = 0; j < DD; ++j) sh[j] = shp[j];
    const float* xp = x + (size_t)s * CD + c;
    float xs[DD];
#pragma unroll
    for (int i = 0; i < DD; ++i) xs[i] = xp[i * 32];
#pragma unroll
    for (int i = 0; i < DD; ++i) {
      float t = wc * xs[i];
#pragma unroll
      for (int j = 0; j < DD; ++j) P[i * DD + j] += t * sh[j];
    }
  }
  float m[DD];
#pragma unroll
  for (int k = 0; k < DD; ++k) m[k] = 0.f;
#pragma unroll
  for (int i = 0; i < DD; ++i) {
#pragma unroll
    for (int j = 0; j < DD; ++j) {
      float p = P[i * DD + j];
#pragma unroll
      for (int k = 0; k < DD; ++k) m[k] += p * CG[i * 81 + j * DD + k];
    }
  }
#pragma unroll
  for (int k = 0; k < DD; ++k) m[k] += __shfl_xor(m[k], 32);
  if (h == 0) {
    float* mp = mpre + (size_t)wid * CD + c;
#pragma unroll
    for (int k = 0; k < DD; ++k) mp[k * 32] = m[k];
  }
}

// ---------------- output linear + self-connection ----------------
__global__ __launch_bounds__(256) void k_out(
    const float* __restrict__ attrs, const float* __restrict__ Wlin,
    const float* __restrict__ Wsc,
    float* __restrict__ out1, float* __restrict__ out2, int N) {
  __shared__ float sWlin[3 * CC * CC];
  __shared__ float sWsc[ZZ * 3 * CC * CC];
  __shared__ float sWn[3 * CC * CC];
  __shared__ float smp[DD * 33];
  __shared__ float smi[DD * 33];
  for (int i = threadIdx.x; i < 3 * CC * CC; i += 256) sWlin[i] = Wlin[i];
  for (int i = threadIdx.x; i < ZZ * 3 * CC * CC; i += 256) sWsc[i] = Wsc[i];
  for (int n = blockIdx.x; n < N; n += gridDim.x) {
    __syncthreads();
    const float* mg = out2 + (size_t)n * CD;
    for (int j = threadIdx.x; j < CD; j += 256) {
      int dd = j >> 5, ccc = j & 31;
      smp[dd * 33 + ccc] = mg[j];
    }
    __syncthreads();
    for (int o = threadIdx.x; o < CD; o += 256) {
      int q = o / 9, d = o - q * 9;
      int l = blk_of(d);
      float acc = 0.f;
#pragma unroll
      for (int c = 0; c < CC; ++c) acc += smp[d * 33 + c] * sWlin[l * 1024 + c * 32 + q];
      acc *= (1.0f / 16.0f);
      smi[d * 33 + q] = acc;
      out1[(size_t)n * CD + o] = acc;
    }
    float a0 = attrs[n * 4 + 0], a1 = attrs[n * 4 + 1];
    float a2 = attrs[n * 4 + 2], a3 = attrs[n * 4 + 3];
    for (int o = threadIdx.x; o < 3 * CC * CC; o += 256) {
      sWn[o] = a0 * sWsc[o] + a1 * sWsc[3072 + o] + a2 * sWsc[2 * 3072 + o] + a3 * sWsc[3 * 3072 + o];
    }
    __syncthreads();
    for (int o = threadIdx.x; o < CD; o += 256) {
      int q = o / 9, d = o - q * 9;
      int l = blk_of(d);
      float acc = 0.f;
#pragma unroll
      for (int c = 0; c < CC; ++c) acc += smi[d * 33 + c] * sWn[l * 1024 + c * 32 + q];
      out2[(size_t)n * CD + o] = acc;
    }
  }
}

extern "C" void kernel_launch(void* const* d_in, const int* in_sizes, int n_in,
                              void* d_out, int out_size, void* d_ws, size_t ws_size,
                              hipStream_t stream) {
  const float* nf    = (const float*)d_in[0];
  const float* attrs = (const float*)d_in[1];
  const float* ef    = (const float*)d_in[2];
  const float* esh   = (const float*)d_in[3];
  const float* cutv  = (const float*)d_in[4];
  const float* Wup   = (const float*)d_in[5];
  const float* W1    = (const float*)d_in[6];
  const float* W2    = (const float*)d_in[7];
  const float* W3    = (const float*)d_in[8];
  const float* Wlin  = (const float*)d_in[9];
  const float* Wsc   = (const float*)d_in[10];
  const float* CG    = (const float*)d_in[11];
  const int* esrc    = (const int*)d_in[12];
  const int* edst    = (const int*)d_in[13];
  int N = in_sizes[0] / CD;
  int E = in_sizes[12];
  float* out1 = (float*)d_out;
  float* out2 = out1 + (size_t)N * CD;   // doubles as the m_pre accumulator

  // workspace layout
  float* x   = (float*)d_ws;                       // N*288 f32
  float* w   = x + (size_t)N * CD;                 // E*32 f32
  int* deg    = (int*)(w + (size_t)E * CC);        // N
  int* offs   = deg + N;                           // N+1
  int* cursor = offs + N + 1;                      // N
  int* eidx   = cursor + N;                        // E

  k_zero<<<(N + 255) / 256, 256, 0, stream>>>((float*)deg, N);
  k_hist<<<(E + 255) / 256, 256, 0, stream>>>(edst, deg, E);
  k_scan<<<1, 1024, 0, stream>>>(deg, offs, cursor, N);
  k_scatter<<<(E + 255) / 256, 256, 0, stream>>>(edst, cursor, eidx, E);
  k_linear_up<<<(N + 7) / 8, 256, 0, stream>>>(nf, Wup, x, N);
  k_mlp<<<(E + 255) / 256, 256, 0, stream>>>(ef, cutv, W1, W2, W3, w, E);
  k_gather<<<(N + 3) / 4, 256, 0, stream>>>(x, w, esh, CG, offs, eidx, esrc, out2, N);
  k_out<<<2048, 256, 0, stream>>>(attrs, Wlin, Wsc, out1, out2, N);
}

// Round 4
// 455.044 us; speedup vs baseline: 1.2803x; 1.2803x over previous
//
#include <hip/hip_runtime.h>
#include <cstdint>

#define CC 32
#define DD 9
#define CD 288   // C*D
#define BB 8
#define HH 64
#define ZZ 4

__device__ __forceinline__ float silu_f(float v) {
  return v / (1.0f + __expf(-v));
}

__device__ __forceinline__ float rlane(float v, int l) {
  return __int_as_float(__builtin_amdgcn_readlane(__float_as_int(v), l));
}

__device__ __forceinline__ int blk_of(int d) { return d == 0 ? 0 : (d < 4 ? 1 : 2); }

__global__ __launch_bounds__(256) void k_zero(float* __restrict__ p, int n) {
  int i = blockIdx.x * 256 + threadIdx.x;
  if (i < n) p[i] = 0.0f;
}

// ---------------- CSR build ----------------
__global__ __launch_bounds__(256) void k_hist(const int* __restrict__ edst,
                                              int* __restrict__ deg, int E) {
  int e = blockIdx.x * 256 + threadIdx.x;
  if (e < E) atomicAdd(&deg[edst[e]], 1);
}

__global__ __launch_bounds__(1024) void k_scan(const int* __restrict__ deg,
                                               int* __restrict__ offs,
                                               int* __restrict__ cursor, int N) {
  __shared__ int part[1024];
  int t = threadIdx.x;
  int chunk = (N + 1023) >> 10;
  int base = t * chunk;
  int lim = N - base; if (lim > chunk) lim = chunk; if (lim < 0) lim = 0;
  int s = 0;
  for (int i = 0; i < lim; ++i) s += deg[base + i];
  part[t] = s;
  __syncthreads();
  for (int off = 1; off < 1024; off <<= 1) {
    int v = part[t];
    int u = (t >= off) ? part[t - off] : 0;
    __syncthreads();
    part[t] = v + u;
    __syncthreads();
  }
  int run = (t == 0) ? 0 : part[t - 1];
  for (int i = 0; i < lim; ++i) {
    offs[base + i] = run;
    cursor[base + i] = run;
    run += deg[base + i];
  }
  if (t == 1023) offs[N] = run;
}

__global__ __launch_bounds__(256) void k_scatter(const int* __restrict__ edst,
                                                 int* __restrict__ cursor,
                                                 int* __restrict__ eidx, int E) {
  int e = blockIdx.x * 256 + threadIdx.x;
  if (e < E) {
    int d = edst[e];
    int pos = atomicAdd(&cursor[d], 1);
    eidx[pos] = e;
  }
}

// ---------------- linear_up: x[n][d][q] = sum_c nf[n][c][d]*Wup[l(d)][c][q] ----------------
// 8 waves; wave w owns d=w (wave 4 also d=8). W-columns in VGPRs, nf row via readlane.
__global__ __launch_bounds__(512, 2) void k_linear_up(
    const float* __restrict__ nf, const float* __restrict__ Wup,
    float* __restrict__ x, int N) {
  __shared__ float snf[CD];
  int t = threadIdx.x;
  int w = t >> 6;
  int lane = t & 63;
  int q = lane & 31;
  bool act = lane < 32;
  int d0 = w;
  int l0 = blk_of(d0);
  float wcol[CC];
#pragma unroll
  for (int c = 0; c < CC; ++c) wcol[c] = Wup[l0 * 1024 + c * 32 + q];
  for (int n = blockIdx.x; n < N; n += gridDim.x) {
    __syncthreads();   // prev-iter snf reads done
    if (t < CD) snf[t] = nf[(size_t)n * CD + t];
    __syncthreads();
    float vm = act ? snf[q * DD + d0] : 0.f;        // lane c holds nf[n][c][d0]
    float vm2 = (w == 4 && act) ? snf[q * DD + 8] : 0.f;
    float acc = 0.f, acc2 = 0.f;
#pragma unroll
    for (int c = 0; c < CC; ++c) {
      acc += rlane(vm, c) * wcol[c];
      if (w == 4) acc2 += rlane(vm2, c) * wcol[c];
    }
    if (act) {
      x[(size_t)n * CD + d0 * 32 + q] = acc;
      if (w == 4) x[(size_t)n * CD + 8 * 32 + q] = acc2;
    }
  }
}

// ---------------- radial MLP: one lane = one edge; weights via s_load; static indices ----------------
__global__ __launch_bounds__(256, 2) void k_mlp(
    const float* __restrict__ ef, const float* __restrict__ cut,
    const float* __restrict__ W1, const float* __restrict__ W2,
    const float* __restrict__ W3, float* __restrict__ w, int E) {
  int e = blockIdx.x * 256 + threadIdx.x;
  if (e >= E) return;
  const float4* efp = (const float4*)(ef + (size_t)e * BB);
  float4 efa = efp[0];
  float4 efb = efp[1];
  float efv[BB] = {efa.x, efa.y, efa.z, efa.w, efb.x, efb.y, efb.z, efb.w};
  // layer 1: acc[q] = sum_k efv[k]*W1[k][q]  (k outer, q inner fully unrolled)
  float acc[HH];
#pragma unroll
  for (int q = 0; q < HH; ++q) acc[q] = 0.f;
#pragma unroll
  for (int k = 0; k < BB; ++k) {
    const float* row = W1 + k * HH;
#pragma unroll
    for (int q = 0; q < HH; ++q) acc[q] += efv[k] * row[q];
  }
  float h1[HH];
#pragma unroll
  for (int q = 0; q < HH; ++q) h1[q] = silu_f(acc[q]);
  // layer 2: acc[q] = sum_k h1[k]*W2[k][q]
#pragma unroll
  for (int q = 0; q < HH; ++q) acc[q] = 0.f;
  for (int k = 0; k < HH; ++k) {   // runtime k: W2 row address uniform -> s_load
    const float* row = W2 + k * HH;
    float hk = h1[k];
#pragma unroll
    for (int q = 0; q < HH; ++q) acc[q] += hk * row[q];
  }
  // silu in place, then layer 3: wacc[c] = sum_q h2[q]*W3[q][c]
  float wacc[CC];
#pragma unroll
  for (int c = 0; c < CC; ++c) wacc[c] = 0.f;
  for (int q = 0; q < HH; ++q) {
    float h2 = silu_f(acc[q]);
    const float* row = W3 + q * CC;
#pragma unroll
    for (int c = 0; c < CC; ++c) wacc[c] += h2 * row[c];
  }
  float cv = cut[e];
  float4* wp = (float4*)(w + (size_t)e * CC);
#pragma unroll
  for (int i = 0; i < 8; ++i) {
    float4 v;
    v.x = wacc[i * 4 + 0] * cv;
    v.y = wacc[i * 4 + 1] * cv;
    v.z = wacc[i * 4 + 2] * cv;
    v.w = wacc[i * 4 + 3] * cv;
    wp[i] = v;
  }
}

// ---------------- gather: one wave per node, halves split even/odd edges ----------------
__global__ __launch_bounds__(256) void k_gather(
    const float* __restrict__ x, const float* __restrict__ w,
    const float* __restrict__ esh, const float* __restrict__ CG,
    const int* __restrict__ offs, const int* __restrict__ eidx,
    const int* __restrict__ esrc, float* __restrict__ mpre, int N) {
  int wid = (blockIdx.x * 256 + threadIdx.x) >> 6;
  if (wid >= N) return;
  int lane = threadIdx.x & 63;
  int h = lane >> 5, c = lane & 31;
  int beg = offs[wid], end = offs[wid + 1];
  float P[81];
#pragma unroll
  for (int i = 0; i < 81; ++i) P[i] = 0.f;
  for (int p0 = beg; p0 < end; p0 += 2) {
    int p = p0 + h;
    bool ok = p < end;
    int pp = ok ? p : p0;
    int e = eidx[pp];
    int s = esrc[e];
    float wc = ok ? w[(size_t)e * CC + c] : 0.f;
    const float* shp = esh + (size_t)e * DD;
    float sh[DD];
#pragma unroll
    for (int j = 0; j < DD; ++j) sh[j] = shp[j];
    const float* xp = x + (size_t)s * CD + c;
    float xs[DD];
#pragma unroll
    for (int i = 0; i < DD; ++i) xs[i] = xp[i * 32];
#pragma unroll
    for (int i = 0; i < DD; ++i) {
      float t = wc * xs[i];
#pragma unroll
      for (int j = 0; j < DD; ++j) P[i * DD + j] += t * sh[j];
    }
  }
  float m[DD];
#pragma unroll
  for (int k = 0; k < DD; ++k) m[k] = 0.f;
#pragma unroll
  for (int i = 0; i < DD; ++i) {
#pragma unroll
    for (int j = 0; j < DD; ++j) {
      float p = P[i * DD + j];
#pragma unroll
      for (int k = 0; k < DD; ++k) m[k] += p * CG[i * 81 + j * DD + k];
    }
  }
#pragma unroll
  for (int k = 0; k < DD; ++k) m[k] += __shfl_xor(m[k], 32);
  if (h == 0) {
    float* mp = mpre + (size_t)wid * CD + c;
#pragma unroll
    for (int k = 0; k < DD; ++k) mp[k * 32] = m[k];
  }
}

// ---------------- output linear + self-connection ----------------
// 8 waves; wave w owns output row d=w (wave 4 also d=8).
// Wsc/Wlin columns persistent in VGPRs; mpre/m_i broadcast via readlane. No LDS.
__global__ __launch_bounds__(512, 2) void k_out(
    const float* __restrict__ attrs, const float* __restrict__ Wlin,
    const float* __restrict__ Wsc,
    float* __restrict__ out1, float* __restrict__ out2, int N) {
  int t = threadIdx.x;
  int w = t >> 6;
  int lane = t & 63;
  int q = lane & 31;
  bool act = lane < 32;
  int d0 = w;
  int l0 = blk_of(d0);
  float wl[CC];     // Wlin[l0][c][q]
#pragma unroll
  for (int c = 0; c < CC; ++c) wl[c] = Wlin[l0 * 1024 + c * 32 + q];
  float ws0[CC], ws1[CC], ws2[CC], ws3[CC];   // Wsc[z][l0][c][q]
#pragma unroll
  for (int c = 0; c < CC; ++c) {
    ws0[c] = Wsc[0 * 3072 + l0 * 1024 + c * 32 + q];
    ws1[c] = Wsc[1 * 3072 + l0 * 1024 + c * 32 + q];
    ws2[c] = Wsc[2 * 3072 + l0 * 1024 + c * 32 + q];
    ws3[c] = Wsc[3 * 3072 + l0 * 1024 + c * 32 + q];
  }
  for (int n = blockIdx.x; n < N; n += gridDim.x) {
    float a0 = attrs[n * 4 + 0], a1 = attrs[n * 4 + 1];
    float a2 = attrs[n * 4 + 2], a3 = attrs[n * 4 + 3];
    // mpre rows (layout [d][c]): lane c holds mpre[d0][c]
    float vm  = act ? out2[(size_t)n * CD + d0 * 32 + q] : 0.f;
    float vm2 = (w == 4 && act) ? out2[(size_t)n * CD + 8 * 32 + q] : 0.f;
    // Wn column for this wave's l0
    float wn[CC];
#pragma unroll
    for (int c = 0; c < CC; ++c)
      wn[c] = a0 * ws0[c] + a1 * ws1[c] + a2 * ws2[c] + a3 * ws3[c];
    // einsum1: m_i[q][d0] = (1/16) sum_c mpre[d0][c]*Wlin[l0][c][q]
    float acc = 0.f, accB = 0.f;
#pragma unroll
    for (int c = 0; c < CC; ++c) {
      acc += rlane(vm, c) * wl[c];
      if (w == 4) accB += rlane(vm2, c) * wl[c];
    }
    acc *= (1.0f / 16.0f);
    accB *= (1.0f / 16.0f);
    // all mpre reads done before any out2 write for this node
    __syncthreads();
    // einsum2: scs[q][d0] = sum_c m_i[c][d0]*Wn[l0][c][q]; m_i[c][d0] = lane c's acc
    float sacc = 0.f, saccB = 0.f;
#pragma unroll
    for (int c = 0; c < CC; ++c) {
      sacc += rlane(acc, c) * wn[c];
      if (w == 4) saccB += rlane(accB, c) * wn[c];
    }
    if (act) {
      out1[(size_t)n * CD + q * DD + d0] = acc;
      out2[(size_t)n * CD + q * DD + d0] = sacc;
      if (w == 4) {
        out1[(size_t)n * CD + q * DD + 8] = accB;
        out2[(size_t)n * CD + q * DD + 8] = saccB;
      }
    }
    __syncthreads();  // writes done before next node (paranoia; regions disjoint)
  }
}

extern "C" void kernel_launch(void* const* d_in, const int* in_sizes, int n_in,
                              void* d_out, int out_size, void* d_ws, size_t ws_size,
                              hipStream_t stream) {
  const float* nf    = (const float*)d_in[0];
  const float* attrs = (const float*)d_in[1];
  const float* ef    = (const float*)d_in[2];
  const float* esh   = (const float*)d_in[3];
  const float* cutv  = (const float*)d_in[4];
  const float* Wup   = (const float*)d_in[5];
  const float* W1    = (const float*)d_in[6];
  const float* W2    = (const float*)d_in[7];
  const float* W3    = (const float*)d_in[8];
  const float* Wlin  = (const float*)d_in[9];
  const float* Wsc   = (const float*)d_in[10];
  const float* CG    = (const float*)d_in[11];
  const int* esrc    = (const int*)d_in[12];
  const int* edst    = (const int*)d_in[13];
  int N = in_sizes[0] / CD;
  int E = in_sizes[12];
  float* out1 = (float*)d_out;
  float* out2 = out1 + (size_t)N * CD;   // doubles as the m_pre accumulator

  float* x   = (float*)d_ws;                       // N*288 f32
  float* w   = x + (size_t)N * CD;                 // E*32 f32
  int* deg    = (int*)(w + (size_t)E * CC);        // N
  int* offs   = deg + N;                           // N+1
  int* cursor = offs + N + 1;                      // N
  int* eidx   = cursor + N;                        // E

  k_zero<<<(N + 255) / 256, 256, 0, stream>>>((float*)deg, N);
  k_hist<<<(E + 255) / 256, 256, 0, stream>>>(edst, deg, E);
  k_scan<<<1, 1024, 0, stream>>>(deg, offs, cursor, N);
  k_scatter<<<(E + 255) / 256, 256, 0, stream>>>(edst, cursor, eidx, E);
  k_linear_up<<<2048, 512, 0, stream>>>(nf, Wup, x, N);
  k_mlp<<<(E + 255) / 256, 256, 0, stream>>>(ef, cutv, W1, W2, W3, w, E);
  k_gather<<<(N + 3) / 4, 256, 0, stream>>>(x, w, esh, CG, offs, eidx, esrc, out2, N);
  k_out<<<1024, 512, 0, stream>>>(attrs, Wlin, Wsc, out1, out2, N);
}

// Round 5
// 335.416 us; speedup vs baseline: 1.7369x; 1.3567x over previous
//
#include <hip/hip_runtime.h>
#include <cstdint>

#define CC 32
#define DD 9
#define CD 288   // C*D
#define BB 8
#define HH 64
#define ZZ 4

__device__ __forceinline__ float silu_f(float v) {
  return v / (1.0f + __expf(-v));
}

__device__ __forceinline__ int blk_of(int d) { return d == 0 ? 0 : (d < 4 ? 1 : 2); }

__global__ __launch_bounds__(256) void k_zero(float* __restrict__ p, int n) {
  int i = blockIdx.x * 256 + threadIdx.x;
  if (i < n) p[i] = 0.0f;
}

// ---------------- CSR build ----------------
__global__ __launch_bounds__(256) void k_hist(const int* __restrict__ edst,
                                              int* __restrict__ deg, int E) {
  int e = blockIdx.x * 256 + threadIdx.x;
  if (e < E) atomicAdd(&deg[edst[e]], 1);
}

__global__ __launch_bounds__(1024) void k_scan(const int* __restrict__ deg,
                                               int* __restrict__ offs,
                                               int* __restrict__ cursor, int N) {
  __shared__ int part[1024];
  int t = threadIdx.x;
  int chunk = (N + 1023) >> 10;
  int base = t * chunk;
  int lim = N - base; if (lim > chunk) lim = chunk; if (lim < 0) lim = 0;
  int s = 0;
  for (int i = 0; i < lim; ++i) s += deg[base + i];
  part[t] = s;
  __syncthreads();
  for (int off = 1; off < 1024; off <<= 1) {
    int v = part[t];
    int u = (t >= off) ? part[t - off] : 0;
    __syncthreads();
    part[t] = v + u;
    __syncthreads();
  }
  int run = (t == 0) ? 0 : part[t - 1];
  for (int i = 0; i < lim; ++i) {
    offs[base + i] = run;
    cursor[base + i] = run;
    run += deg[base + i];
  }
  if (t == 1023) offs[N] = run;
}

__global__ __launch_bounds__(256) void k_scatter(const int* __restrict__ edst,
                                                 int* __restrict__ cursor,
                                                 int* __restrict__ eidx, int E) {
  int e = blockIdx.x * 256 + threadIdx.x;
  if (e < E) {
    int d = edst[e];
    int pos = atomicAdd(&cursor[d], 1);
    eidx[pos] = e;
  }
}

// ---------------- linear_up ----------------
// 288 threads: thread (q,g) computes x[n][d=g][q] = sum_c nf[n][c][g]*Wup[l(g)][c][q]
__global__ __launch_bounds__(288) void k_linear_up(
    const float* __restrict__ nf, const float* __restrict__ Wup,
    float* __restrict__ x, int N) {
  __shared__ float snf[DD * 36];   // transposed [d][c], row stride 36 (16B-aligned)
  int t = threadIdx.x;
  int g = t >> 5, q = t & 31;
  int tc = t / 9, td = t - tc * 9;
  int l0 = blk_of(g);
  float wcol[CC];
#pragma unroll
  for (int c = 0; c < CC; ++c) wcol[c] = Wup[l0 * 1024 + c * 32 + q];
  for (int n = blockIdx.x; n < N; n += gridDim.x) {
    __syncthreads();                       // prev-iter snf reads done
    snf[td * 36 + tc] = nf[(size_t)n * CD + t];
    __syncthreads();
    const float4* rowp = (const float4*)(snf + g * 36);
    float a0 = 0.f, a1 = 0.f;
#pragma unroll
    for (int c4 = 0; c4 < 8; ++c4) {
      float4 b = rowp[c4];
      a0 += b.x * wcol[c4 * 4 + 0] + b.y * wcol[c4 * 4 + 1];
      a1 += b.z * wcol[c4 * 4 + 2] + b.w * wcol[c4 * 4 + 3];
    }
    x[(size_t)n * CD + t] = a0 + a1;       // [d][c] layout, addr = t -> coalesced
  }
}

// ---------------- radial MLP: one lane = one edge; static indices; s_load weights ----------------
__global__ __launch_bounds__(256, 2) void k_mlp(
    const float* __restrict__ ef, const float* __restrict__ cut,
    const float* __restrict__ W1, const float* __restrict__ W2,
    const float* __restrict__ W3, float* __restrict__ w, int E) {
  int e = blockIdx.x * 256 + threadIdx.x;
  if (e >= E) return;
  const float4* efp = (const float4*)(ef + (size_t)e * BB);
  float4 efa = efp[0];
  float4 efb = efp[1];
  float efv[BB] = {efa.x, efa.y, efa.z, efa.w, efb.x, efb.y, efb.z, efb.w};
  float acc[HH];
#pragma unroll
  for (int q = 0; q < HH; ++q) acc[q] = 0.f;
#pragma unroll
  for (int k = 0; k < BB; ++k) {
    const float* row = W1 + k * HH;
#pragma unroll
    for (int q = 0; q < HH; ++q) acc[q] += efv[k] * row[q];
  }
  float h1[HH];
#pragma unroll
  for (int q = 0; q < HH; ++q) h1[q] = silu_f(acc[q]);
#pragma unroll
  for (int q = 0; q < HH; ++q) acc[q] = 0.f;
  for (int k = 0; k < HH; ++k) {   // runtime k: W2 row address wave-uniform -> s_load
    const float* row = W2 + k * HH;
    float hk = h1[k];
#pragma unroll
    for (int q = 0; q < HH; ++q) acc[q] += hk * row[q];
  }
  float wacc[CC];
#pragma unroll
  for (int c = 0; c < CC; ++c) wacc[c] = 0.f;
  for (int q = 0; q < HH; ++q) {
    float h2 = silu_f(acc[q]);
    const float* row = W3 + q * CC;
#pragma unroll
    for (int c = 0; c < CC; ++c) wacc[c] += h2 * row[c];
  }
  float cv = cut[e];
  float4* wp = (float4*)(w + (size_t)e * CC);
#pragma unroll
  for (int i = 0; i < 8; ++i) {
    float4 v;
    v.x = wacc[i * 4 + 0] * cv;
    v.y = wacc[i * 4 + 1] * cv;
    v.z = wacc[i * 4 + 2] * cv;
    v.w = wacc[i * 4 + 3] * cv;
    wp[i] = v;
  }
}

// ---------------- gather: one wave per node, halves split even/odd edges ----------------
__global__ __launch_bounds__(256) void k_gather(
    const float* __restrict__ x, const float* __restrict__ w,
    const float* __restrict__ esh, const float* __restrict__ CG,
    const int* __restrict__ offs, const int* __restrict__ eidx,
    const int* __restrict__ esrc, float* __restrict__ mpre, int N) {
  int wid = (blockIdx.x * 256 + threadIdx.x) >> 6;
  if (wid >= N) return;
  int lane = threadIdx.x & 63;
  int h = lane >> 5, c = lane & 31;
  int beg = offs[wid], end = offs[wid + 1];
  float P[81];
#pragma unroll
  for (int i = 0; i < 81; ++i) P[i] = 0.f;
  for (int p0 = beg; p0 < end; p0 += 2) {
    int p = p0 + h;
    bool ok = p < end;
    int pp = ok ? p : p0;
    int e = eidx[pp];
    int s = esrc[e];
    float wc = ok ? w[(size_t)e * CC + c] : 0.f;
    const float* shp = esh + (size_t)e * DD;
    float sh[DD];
#pragma unroll
    for (int j = 0; j < DD; ++j) sh[j] = shp[j];
    const float* xp = x + (size_t)s * CD + c;
    float xs[DD];
#pragma unroll
    for (int i = 0; i < DD; ++i) xs[i] = xp[i * 32];
#pragma unroll
    for (int i = 0; i < DD; ++i) {
      float t = wc * xs[i];
#pragma unroll
      for (int j = 0; j < DD; ++j) P[i * DD + j] += t * sh[j];
    }
  }
  float m[DD];
#pragma unroll
  for (int k = 0; k < DD; ++k) m[k] = 0.f;
#pragma unroll
  for (int i = 0; i < DD; ++i) {
#pragma unroll
    for (int j = 0; j < DD; ++j) {
      float p = P[i * DD + j];
#pragma unroll
      for (int k = 0; k < DD; ++k) m[k] += p * CG[i * 81 + j * DD + k];
    }
  }
#pragma unroll
  for (int k = 0; k < DD; ++k) m[k] += __shfl_xor(m[k], 32);
  if (h == 0) {
    float* mp = mpre + (size_t)wid * CD + c;
#pragma unroll
    for (int k = 0; k < DD; ++k) mp[k * 32] = m[k];
  }
}

// ---------------- k_out1: m_i = block_linear(mpre, Wlin)/16 ----------------
// 288 threads: thread (q,g) computes m_i[q][g]; writes out1 (ref layout, via LDS
// bounce) and m_t[n][g][q] (transposed, coalesced) for k_out2.
__global__ __launch_bounds__(288) void k_out1(
    const float* __restrict__ mpre, const float* __restrict__ Wlin,
    float* __restrict__ out1, float* __restrict__ m_t, int N) {
  __shared__ float smp[CD];
  __shared__ float sres[CD];
  int t = threadIdx.x;
  int g = t >> 5, q = t & 31;
  int l0 = blk_of(g);
  float wl[CC];
#pragma unroll
  for (int c = 0; c < CC; ++c) wl[c] = Wlin[l0 * 1024 + c * 32 + q];
  for (int n = blockIdx.x; n < N; n += gridDim.x) {
    __syncthreads();                         // prev smp/sres reads done
    smp[t] = mpre[(size_t)n * CD + t];       // [d][c], addr=t -> coalesced
    __syncthreads();
    const float4* rowp = (const float4*)(smp + g * 32);
    float a0 = 0.f, a1 = 0.f;
#pragma unroll
    for (int c4 = 0; c4 < 8; ++c4) {
      float4 b = rowp[c4];
      a0 += b.x * wl[c4 * 4 + 0] + b.y * wl[c4 * 4 + 1];
      a1 += b.z * wl[c4 * 4 + 2] + b.w * wl[c4 * 4 + 3];
    }
    float v = (a0 + a1) * (1.0f / 16.0f);
    m_t[(size_t)n * CD + t] = v;             // [d][c] layout, coalesced
    sres[q * DD + g] = v;                    // 9 coprime 32 -> conflict-free
    __syncthreads();
    if (t < 72) {
      float4 o = ((const float4*)sres)[t];
      ((float4*)(out1 + (size_t)n * CD))[t] = o;   // coalesced ref-layout store
    }
  }
}

// ---------------- k_out2: scs from m_t and element-dependent Wsc ----------------
// z-reordered: scs[q][d] = sum_z a_z * (sum_c m_t[d][c] * Wsc[z][l][c][q])
__global__ __launch_bounds__(288) void k_out2(
    const float* __restrict__ attrs, const float* __restrict__ Wsc,
    const float* __restrict__ m_t, float* __restrict__ out2, int N) {
  __shared__ float smt[CD];
  __shared__ float sres[CD];
  int t = threadIdx.x;
  int g = t >> 5, q = t & 31;
  int l0 = blk_of(g);
  float ws0[CC], ws1[CC], ws2[CC], ws3[CC];
#pragma unroll
  for (int c = 0; c < CC; ++c) {
    ws0[c] = Wsc[0 * 3072 + l0 * 1024 + c * 32 + q];
    ws1[c] = Wsc[1 * 3072 + l0 * 1024 + c * 32 + q];
    ws2[c] = Wsc[2 * 3072 + l0 * 1024 + c * 32 + q];
    ws3[c] = Wsc[3 * 3072 + l0 * 1024 + c * 32 + q];
  }
  for (int n = blockIdx.x; n < N; n += gridDim.x) {
    __syncthreads();
    smt[t] = m_t[(size_t)n * CD + t];
    float a0 = attrs[n * 4 + 0], a1 = attrs[n * 4 + 1];
    float a2 = attrs[n * 4 + 2], a3 = attrs[n * 4 + 3];
    __syncthreads();
    const float4* rowp = (const float4*)(smt + g * 32);
    float z0 = 0.f, z1 = 0.f, z2 = 0.f, z3 = 0.f;
#pragma unroll
    for (int c4 = 0; c4 < 8; ++c4) {
      float4 b = rowp[c4];
#pragma unroll
      for (int j = 0; j < 4; ++j) {
        float bv = (j == 0) ? b.x : (j == 1) ? b.y : (j == 2) ? b.z : b.w;
        int c = c4 * 4 + j;
        z0 += bv * ws0[c];
        z1 += bv * ws1[c];
        z2 += bv * ws2[c];
        z3 += bv * ws3[c];
      }
    }
    sres[q * DD + g] = a0 * z0 + a1 * z1 + a2 * z2 + a3 * z3;
    __syncthreads();
    if (t < 72) {
      float4 o = ((const float4*)sres)[t];
      ((float4*)(out2 + (size_t)n * CD))[t] = o;
    }
  }
}

extern "C" void kernel_launch(void* const* d_in, const int* in_sizes, int n_in,
                              void* d_out, int out_size, void* d_ws, size_t ws_size,
                              hipStream_t stream) {
  const float* nf    = (const float*)d_in[0];
  const float* attrs = (const float*)d_in[1];
  const float* ef    = (const float*)d_in[2];
  const float* esh   = (const float*)d_in[3];
  const float* cutv  = (const float*)d_in[4];
  const float* Wup   = (const float*)d_in[5];
  const float* W1    = (const float*)d_in[6];
  const float* W2    = (const float*)d_in[7];
  const float* W3    = (const float*)d_in[8];
  const float* Wlin  = (const float*)d_in[9];
  const float* Wsc   = (const float*)d_in[10];
  const float* CG    = (const float*)d_in[11];
  const int* esrc    = (const int*)d_in[12];
  const int* edst    = (const int*)d_in[13];
  int N = in_sizes[0] / CD;
  int E = in_sizes[12];
  float* out1 = (float*)d_out;
  float* out2 = out1 + (size_t)N * CD;   // doubles as the m_pre accumulator

  float* x   = (float*)d_ws;                       // N*288 f32 (also reused as m_t)
  float* w   = x + (size_t)N * CD;                 // E*32 f32
  int* deg    = (int*)(w + (size_t)E * CC);        // N
  int* offs   = deg + N;                           // N+1
  int* cursor = offs + N + 1;                      // N
  int* eidx   = cursor + N;                        // E
  float* m_t = x;   // safe alias: x fully consumed by k_gather before k_out1 writes

  k_zero<<<(N + 255) / 256, 256, 0, stream>>>((float*)deg, N);
  k_hist<<<(E + 255) / 256, 256, 0, stream>>>(edst, deg, E);
  k_scan<<<1, 1024, 0, stream>>>(deg, offs, cursor, N);
  k_scatter<<<(E + 255) / 256, 256, 0, stream>>>(edst, cursor, eidx, E);
  k_linear_up<<<2048, 288, 0, stream>>>(nf, Wup, x, N);
  k_mlp<<<(E + 255) / 256, 256, 0, stream>>>(ef, cutv, W1, W2, W3, w, E);
  k_gather<<<(N + 3) / 4, 256, 0, stream>>>(x, w, esh, CG, offs, eidx, esrc, out2, N);
  k_out1<<<2048, 288, 0, stream>>>(out2, Wlin, out1, m_t, N);
  k_out2<<<2048, 288, 0, stream>>>(attrs, Wsc, m_t, out2, N);
}

// Round 6
// 327.333 us; speedup vs baseline: 1.7798x; 1.0247x over previous
//
#include <hip/hip_runtime.h>
#include <cstdint>

#define CC 32
#define DD 9
#define CD 288   // C*D
#define BB 8
#define HH 64
#define ZZ 4

__device__ __forceinline__ float silu_f(float v) {
  return v / (1.0f + __expf(-v));
}

__device__ __forceinline__ int blk_of(int d) { return d == 0 ? 0 : (d < 4 ? 1 : 2); }

__global__ __launch_bounds__(256) void k_zero(float* __restrict__ p, int n) {
  int i = blockIdx.x * 256 + threadIdx.x;
  if (i < n) p[i] = 0.0f;
}

// ---------------- CSR build ----------------
__global__ __launch_bounds__(256) void k_hist(const int* __restrict__ edst,
                                              int* __restrict__ deg, int E) {
  int e = blockIdx.x * 256 + threadIdx.x;
  if (e < E) atomicAdd(&deg[edst[e]], 1);
}

__global__ __launch_bounds__(1024) void k_scan(const int* __restrict__ deg,
                                               int* __restrict__ offs,
                                               int* __restrict__ cursor, int N) {
  __shared__ int part[1024];
  int t = threadIdx.x;
  int chunk = (N + 1023) >> 10;
  int base = t * chunk;
  int lim = N - base; if (lim > chunk) lim = chunk; if (lim < 0) lim = 0;
  int s = 0;
  for (int i = 0; i < lim; ++i) s += deg[base + i];
  part[t] = s;
  __syncthreads();
  for (int off = 1; off < 1024; off <<= 1) {
    int v = part[t];
    int u = (t >= off) ? part[t - off] : 0;
    __syncthreads();
    part[t] = v + u;
    __syncthreads();
  }
  int run = (t == 0) ? 0 : part[t - 1];
  for (int i = 0; i < lim; ++i) {
    offs[base + i] = run;
    cursor[base + i] = run;
    run += deg[base + i];
  }
  if (t == 1023) offs[N] = run;
}

__global__ __launch_bounds__(256) void k_scatter(const int* __restrict__ edst,
                                                 int* __restrict__ cursor,
                                                 int* __restrict__ eidx, int E) {
  int e = blockIdx.x * 256 + threadIdx.x;
  if (e < E) {
    int d = edst[e];
    int pos = atomicAdd(&cursor[d], 1);
    eidx[pos] = e;
  }
}

// ---------------- linear_up ----------------
__global__ __launch_bounds__(288) void k_linear_up(
    const float* __restrict__ nf, const float* __restrict__ Wup,
    float* __restrict__ x, int N) {
  __shared__ float snf[DD * 36];
  int t = threadIdx.x;
  int g = t >> 5, q = t & 31;
  int tc = t / 9, td = t - tc * 9;
  int l0 = blk_of(g);
  float wcol[CC];
#pragma unroll
  for (int c = 0; c < CC; ++c) wcol[c] = Wup[l0 * 1024 + c * 32 + q];
  for (int n = blockIdx.x; n < N; n += gridDim.x) {
    __syncthreads();
    snf[td * 36 + tc] = nf[(size_t)n * CD + t];
    __syncthreads();
    const float4* rowp = (const float4*)(snf + g * 36);
    float a0 = 0.f, a1 = 0.f;
#pragma unroll
    for (int c4 = 0; c4 < 8; ++c4) {
      float4 b = rowp[c4];
      a0 += b.x * wcol[c4 * 4 + 0] + b.y * wcol[c4 * 4 + 1];
      a1 += b.z * wcol[c4 * 4 + 2] + b.w * wcol[c4 * 4 + 3];
    }
    x[(size_t)n * CD + t] = a0 + a1;
  }
}

// ---------------- radial MLP: one lane = one edge; ALL loops fully unrolled ----------------
// Every array index compile-time -> registers only; weight addresses uniform -> s_load.
__global__ __launch_bounds__(256) void k_mlp(
    const float* __restrict__ ef, const float* __restrict__ cut,
    const float* __restrict__ W1, const float* __restrict__ W2,
    const float* __restrict__ W3, float* __restrict__ w, int E) {
  int e = blockIdx.x * 256 + threadIdx.x;
  if (e >= E) return;
  const float4* efp = (const float4*)(ef + (size_t)e * BB);
  float4 efa = efp[0];
  float4 efb = efp[1];
  float efv[BB] = {efa.x, efa.y, efa.z, efa.w, efb.x, efb.y, efb.z, efb.w};
  // layer 1
  float acc[HH];
#pragma unroll
  for (int q = 0; q < HH; ++q) acc[q] = 0.f;
#pragma unroll
  for (int k = 0; k < BB; ++k) {
#pragma unroll
    for (int q = 0; q < HH; ++q) acc[q] += efv[k] * W1[k * HH + q];
  }
  float h1[HH];
#pragma unroll
  for (int q = 0; q < HH; ++q) h1[q] = silu_f(acc[q]);
  // layer 2 (fully unrolled: h1[k] static -> registers)
#pragma unroll
  for (int q = 0; q < HH; ++q) acc[q] = 0.f;
#pragma unroll
  for (int k = 0; k < HH; ++k) {
#pragma unroll
    for (int q = 0; q < HH; ++q) acc[q] += h1[k] * W2[k * HH + q];
  }
  // layer 3 (fully unrolled: acc[q] static -> registers)
  float wacc[CC];
#pragma unroll
  for (int c = 0; c < CC; ++c) wacc[c] = 0.f;
#pragma unroll
  for (int q = 0; q < HH; ++q) {
    float h2 = silu_f(acc[q]);
#pragma unroll
    for (int c = 0; c < CC; ++c) wacc[c] += h2 * W3[q * CC + c];
  }
  float cv = cut[e];
  float4* wp = (float4*)(w + (size_t)e * CC);
#pragma unroll
  for (int i = 0; i < 8; ++i) {
    float4 v;
    v.x = wacc[i * 4 + 0] * cv;
    v.y = wacc[i * 4 + 1] * cv;
    v.z = wacc[i * 4 + 2] * cv;
    v.w = wacc[i * 4 + 3] * cv;
    wp[i] = v;
  }
}

// ---------------- gather: one wave per node, halves split even/odd edges ----------------
__global__ __launch_bounds__(256) void k_gather(
    const float* __restrict__ x, const float* __restrict__ w,
    const float* __restrict__ esh, const float* __restrict__ CG,
    const int* __restrict__ offs, const int* __restrict__ eidx,
    const int* __restrict__ esrc, float* __restrict__ mpre, int N) {
  int wid = (blockIdx.x * 256 + threadIdx.x) >> 6;
  if (wid >= N) return;
  int lane = threadIdx.x & 63;
  int h = lane >> 5, c = lane & 31;
  int beg = offs[wid], end = offs[wid + 1];
  float P[81];
#pragma unroll
  for (int i = 0; i < 81; ++i) P[i] = 0.f;
  for (int p0 = beg; p0 < end; p0 += 2) {
    int p = p0 + h;
    bool ok = p < end;
    int pp = ok ? p : p0;
    int e = eidx[pp];
    int s = esrc[e];
    float wc = ok ? w[(size_t)e * CC + c] : 0.f;
    const float* shp = esh + (size_t)e * DD;
    float sh[DD];
#pragma unroll
    for (int j = 0; j < DD; ++j) sh[j] = shp[j];
    const float* xp = x + (size_t)s * CD + c;
    float xs[DD];
#pragma unroll
    for (int i = 0; i < DD; ++i) xs[i] = xp[i * 32];
#pragma unroll
    for (int i = 0; i < DD; ++i) {
      float t = wc * xs[i];
#pragma unroll
      for (int j = 0; j < DD; ++j) P[i * DD + j] += t * sh[j];
    }
  }
  float m[DD];
#pragma unroll
  for (int k = 0; k < DD; ++k) m[k] = 0.f;
#pragma unroll
  for (int i = 0; i < DD; ++i) {
#pragma unroll
    for (int j = 0; j < DD; ++j) {
      float p = P[i * DD + j];
#pragma unroll
      for (int k = 0; k < DD; ++k) m[k] += p * CG[i * 81 + j * DD + k];
    }
  }
#pragma unroll
  for (int k = 0; k < DD; ++k) m[k] += __shfl_xor(m[k], 32);
  if (h == 0) {
    float* mp = mpre + (size_t)wid * CD + c;
#pragma unroll
    for (int k = 0; k < DD; ++k) mp[k * 32] = m[k];
  }
}

// ---------------- k_out1: m_i = block_linear(mpre, Wlin)/16 ----------------
__global__ __launch_bounds__(288) void k_out1(
    const float* __restrict__ mpre, const float* __restrict__ Wlin,
    float* __restrict__ out1, float* __restrict__ m_t, int N) {
  __shared__ float smp[CD];
  __shared__ float sres[CD];
  int t = threadIdx.x;
  int g = t >> 5, q = t & 31;
  int l0 = blk_of(g);
  float wl[CC];
#pragma unroll
  for (int c = 0; c < CC; ++c) wl[c] = Wlin[l0 * 1024 + c * 32 + q];
  for (int n = blockIdx.x; n < N; n += gridDim.x) {
    __syncthreads();
    smp[t] = mpre[(size_t)n * CD + t];
    __syncthreads();
    const float4* rowp = (const float4*)(smp + g * 32);
    float a0 = 0.f, a1 = 0.f;
#pragma unroll
    for (int c4 = 0; c4 < 8; ++c4) {
      float4 b = rowp[c4];
      a0 += b.x * wl[c4 * 4 + 0] + b.y * wl[c4 * 4 + 1];
      a1 += b.z * wl[c4 * 4 + 2] + b.w * wl[c4 * 4 + 3];
    }
    float v = (a0 + a1) * (1.0f / 16.0f);
    m_t[(size_t)n * CD + t] = v;
    sres[q * DD + g] = v;
    __syncthreads();
    if (t < 72) {
      float4 o = ((const float4*)sres)[t];
      ((float4*)(out1 + (size_t)n * CD))[t] = o;
    }
  }
}

// ---------------- k_out2: scs from m_t and element-dependent Wsc ----------------
__global__ __launch_bounds__(288) void k_out2(
    const float* __restrict__ attrs, const float* __restrict__ Wsc,
    const float* __restrict__ m_t, float* __restrict__ out2, int N) {
  __shared__ float smt[CD];
  __shared__ float sres[CD];
  int t = threadIdx.x;
  int g = t >> 5, q = t & 31;
  int l0 = blk_of(g);
  float ws0[CC], ws1[CC], ws2[CC], ws3[CC];
#pragma unroll
  for (int c = 0; c < CC; ++c) {
    ws0[c] = Wsc[0 * 3072 + l0 * 1024 + c * 32 + q];
    ws1[c] = Wsc[1 * 3072 + l0 * 1024 + c * 32 + q];
    ws2[c] = Wsc[2 * 3072 + l0 * 1024 + c * 32 + q];
    ws3[c] = Wsc[3 * 3072 + l0 * 1024 + c * 32 + q];
  }
  for (int n = blockIdx.x; n < N; n += gridDim.x) {
    __syncthreads();
    smt[t] = m_t[(size_t)n * CD + t];
    float a0 = attrs[n * 4 + 0], a1 = attrs[n * 4 + 1];
    float a2 = attrs[n * 4 + 2], a3 = attrs[n * 4 + 3];
    __syncthreads();
    const float4* rowp = (const float4*)(smt + g * 32);
    float z0 = 0.f, z1 = 0.f, z2 = 0.f, z3 = 0.f;
#pragma unroll
    for (int c4 = 0; c4 < 8; ++c4) {
      float4 b = rowp[c4];
#pragma unroll
      for (int j = 0; j < 4; ++j) {
        float bv = (j == 0) ? b.x : (j == 1) ? b.y : (j == 2) ? b.z : b.w;
        int c = c4 * 4 + j;
        z0 += bv * ws0[c];
        z1 += bv * ws1[c];
        z2 += bv * ws2[c];
        z3 += bv * ws3[c];
      }
    }
    sres[q * DD + g] = a0 * z0 + a1 * z1 + a2 * z2 + a3 * z3;
    __syncthreads();
    if (t < 72) {
      float4 o = ((const float4*)sres)[t];
      ((float4*)(out2 + (size_t)n * CD))[t] = o;
    }
  }
}

extern "C" void kernel_launch(void* const* d_in, const int* in_sizes, int n_in,
                              void* d_out, int out_size, void* d_ws, size_t ws_size,
                              hipStream_t stream) {
  const float* nf    = (const float*)d_in[0];
  const float* attrs = (const float*)d_in[1];
  const float* ef    = (const float*)d_in[2];
  const float* esh   = (const float*)d_in[3];
  const float* cutv  = (const float*)d_in[4];
  const float* Wup   = (const float*)d_in[5];
  const float* W1    = (const float*)d_in[6];
  const float* W2    = (const float*)d_in[7];
  const float* W3    = (const float*)d_in[8];
  const float* Wlin  = (const float*)d_in[9];
  const float* Wsc   = (const float*)d_in[10];
  const float* CG    = (const float*)d_in[11];
  const int* esrc    = (const int*)d_in[12];
  const int* edst    = (const int*)d_in[13];
  int N = in_sizes[0] / CD;
  int E = in_sizes[12];
  float* out1 = (float*)d_out;
  float* out2 = out1 + (size_t)N * CD;   // doubles as the m_pre accumulator

  float* x   = (float*)d_ws;                       // N*288 f32 (also reused as m_t)
  float* w   = x + (size_t)N * CD;                 // E*32 f32
  int* deg    = (int*)(w + (size_t)E * CC);        // N
  int* offs   = deg + N;                           // N+1
  int* cursor = offs + N + 1;                      // N
  int* eidx   = cursor + N;                        // E
  float* m_t = x;   // safe alias: x fully consumed by k_gather before k_out1 writes

  k_zero<<<(N + 255) / 256, 256, 0, stream>>>((float*)deg, N);
  k_hist<<<(E + 255) / 256, 256, 0, stream>>>(edst, deg, E);
  k_scan<<<1, 1024, 0, stream>>>(deg, offs, cursor, N);
  k_scatter<<<(E + 255) / 256, 256, 0, stream>>>(edst, cursor, eidx, E);
  k_linear_up<<<2048, 288, 0, stream>>>(nf, Wup, x, N);
  k_mlp<<<(E + 255) / 256, 256, 0, stream>>>(ef, cutv, W1, W2, W3, w, E);
  k_gather<<<(N + 3) / 4, 256, 0, stream>>>(x, w, esh, CG, offs, eidx, esrc, out2, N);
  k_out1<<<2048, 288, 0, stream>>>(out2, Wlin, out1, m_t, N);
  k_out2<<<2048, 288, 0, stream>>>(attrs, Wsc, m_t, out2, N);
}

// Round 7
// 317.877 us; speedup vs baseline: 1.8327x; 1.0297x over previous
//
#include <hip/hip_runtime.h>
#include <cstdint>

#define CC 32
#define DD 9
#define CD 288   // C*D
#define BB 8
#define HH 64
#define ZZ 4

__device__ __forceinline__ float silu_f(float v) {
  return v / (1.0f + __expf(-v));
}

__device__ __forceinline__ int blk_of(int d) { return d == 0 ? 0 : (d < 4 ? 1 : 2); }

__global__ __launch_bounds__(256) void k_zero(float* __restrict__ p, int n) {
  int i = blockIdx.x * 256 + threadIdx.x;
  if (i < n) p[i] = 0.0f;
}

// ---------------- CSR build ----------------
__global__ __launch_bounds__(256) void k_hist(const int* __restrict__ edst,
                                              int* __restrict__ deg, int E) {
  int e = blockIdx.x * 256 + threadIdx.x;
  if (e < E) atomicAdd(&deg[edst[e]], 1);
}

__global__ __launch_bounds__(1024) void k_scan(const int* __restrict__ deg,
                                               int* __restrict__ offs,
                                               int* __restrict__ cursor, int N) {
  __shared__ int part[1024];
  int t = threadIdx.x;
  int chunk = (N + 1023) >> 10;
  int base = t * chunk;
  int lim = N - base; if (lim > chunk) lim = chunk; if (lim < 0) lim = 0;
  int s = 0;
  for (int i = 0; i < lim; ++i) s += deg[base + i];
  part[t] = s;
  __syncthreads();
  for (int off = 1; off < 1024; off <<= 1) {
    int v = part[t];
    int u = (t >= off) ? part[t - off] : 0;
    __syncthreads();
    part[t] = v + u;
    __syncthreads();
  }
  int run = (t == 0) ? 0 : part[t - 1];
  for (int i = 0; i < lim; ++i) {
    offs[base + i] = run;
    cursor[base + i] = run;
    run += deg[base + i];
  }
  if (t == 1023) offs[N] = run;
}

__global__ __launch_bounds__(256) void k_scatter(const int* __restrict__ edst,
                                                 int* __restrict__ cursor,
                                                 int* __restrict__ eidx, int E) {
  int e = blockIdx.x * 256 + threadIdx.x;
  if (e < E) {
    int d = edst[e];
    int pos = atomicAdd(&cursor[d], 1);
    eidx[pos] = e;
  }
}

// ---------------- transpose W2 (one-shot, 16 blocks) ----------------
__global__ __launch_bounds__(256) void k_w2t(const float* __restrict__ W2,
                                             float* __restrict__ W2T) {
  int t = blockIdx.x * 256 + threadIdx.x;   // t = q*64 + k
  int q = t >> 6, k = t & 63;
  W2T[t] = W2[k * HH + q];
}

// ---------------- linear_up ----------------
__global__ __launch_bounds__(288) void k_linear_up(
    const float* __restrict__ nf, const float* __restrict__ Wup,
    float* __restrict__ x, int N) {
  __shared__ float snf[DD * 36];
  int t = threadIdx.x;
  int g = t >> 5, q = t & 31;
  int tc = t / 9, td = t - tc * 9;
  int l0 = blk_of(g);
  float wcol[CC];
#pragma unroll
  for (int c = 0; c < CC; ++c) wcol[c] = Wup[l0 * 1024 + c * 32 + q];
  for (int n = blockIdx.x; n < N; n += gridDim.x) {
    __syncthreads();
    snf[td * 36 + tc] = nf[(size_t)n * CD + t];
    __syncthreads();
    const float4* rowp = (const float4*)(snf + g * 36);
    float a0 = 0.f, a1 = 0.f;
#pragma unroll
    for (int c4 = 0; c4 < 8; ++c4) {
      float4 b = rowp[c4];
      a0 += b.x * wcol[c4 * 4 + 0] + b.y * wcol[c4 * 4 + 1];
      a1 += b.z * wcol[c4 * 4 + 2] + b.w * wcol[c4 * 4 + 3];
    }
    x[(size_t)n * CD + t] = a0 + a1;
  }
}

// ---------------- radial MLP v3: small q-loop, static register indices ----------------
__global__ __launch_bounds__(256) void k_mlp(
    const float* __restrict__ ef, const float* __restrict__ cut,
    const float* __restrict__ W1, const float* __restrict__ W2T,
    const float* __restrict__ W3, float* __restrict__ w, int E) {
  int e = blockIdx.x * 256 + threadIdx.x;
  if (e >= E) return;
  const float4* efp = (const float4*)(ef + (size_t)e * BB);
  float4 efa = efp[0];
  float4 efb = efp[1];
  float efv[BB] = {efa.x, efa.y, efa.z, efa.w, efb.x, efb.y, efb.z, efb.w};
  // layer 1: fully unrolled (h1 writes static)
  float h1[HH];
#pragma unroll
  for (int q = 0; q < HH; ++q) {
    float a = 0.f;
#pragma unroll
    for (int k = 0; k < BB; ++k) a += efv[k] * W1[k * HH + q];
    h1[q] = silu_f(a);
  }
  // layers 2+3: runtime q-loop, tiny body; all register indices static
  float wacc[CC];
#pragma unroll
  for (int c = 0; c < CC; ++c) wacc[c] = 0.f;
  for (int q = 0; q < HH; ++q) {
    const float* r2 = W2T + q * HH;   // contiguous row, uniform -> s_load_dwordx16
    float a0 = 0.f, a1 = 0.f, a2 = 0.f, a3 = 0.f;
#pragma unroll
    for (int k = 0; k < HH; k += 4) {
      a0 += h1[k + 0] * r2[k + 0];
      a1 += h1[k + 1] * r2[k + 1];
      a2 += h1[k + 2] * r2[k + 2];
      a3 += h1[k + 3] * r2[k + 3];
    }
    float h2 = silu_f((a0 + a1) + (a2 + a3));
    const float* r3 = W3 + q * CC;    // contiguous row, uniform -> s_load
#pragma unroll
    for (int c = 0; c < CC; ++c) wacc[c] += h2 * r3[c];
  }
  float cv = cut[e];
  float4* wp = (float4*)(w + (size_t)e * CC);
#pragma unroll
  for (int i = 0; i < 8; ++i) {
    float4 v;
    v.x = wacc[i * 4 + 0] * cv;
    v.y = wacc[i * 4 + 1] * cv;
    v.z = wacc[i * 4 + 2] * cv;
    v.w = wacc[i * 4 + 3] * cv;
    wp[i] = v;
  }
}

// ---------------- gather: one wave per node, halves split even/odd edges ----------------
__global__ __launch_bounds__(256) void k_gather(
    const float* __restrict__ x, const float* __restrict__ w,
    const float* __restrict__ esh, const float* __restrict__ CG,
    const int* __restrict__ offs, const int* __restrict__ eidx,
    const int* __restrict__ esrc, float* __restrict__ mpre, int N) {
  int wid = (blockIdx.x * 256 + threadIdx.x) >> 6;
  if (wid >= N) return;
  int lane = threadIdx.x & 63;
  int h = lane >> 5, c = lane & 31;
  int beg = offs[wid], end = offs[wid + 1];
  float P[81];
#pragma unroll
  for (int i = 0; i < 81; ++i) P[i] = 0.f;
  for (int p0 = beg; p0 < end; p0 += 2) {
    int p = p0 + h;
    bool ok = p < end;
    int pp = ok ? p : p0;
    int e = eidx[pp];
    int s = esrc[e];
    float wc = ok ? w[(size_t)e * CC + c] : 0.f;
    const float* shp = esh + (size_t)e * DD;
    float sh[DD];
#pragma unroll
    for (int j = 0; j < DD; ++j) sh[j] = shp[j];
    const float* xp = x + (size_t)s * CD + c;
    float xs[DD];
#pragma unroll
    for (int i = 0; i < DD; ++i) xs[i] = xp[i * 32];
#pragma unroll
    for (int i = 0; i < DD; ++i) {
      float t = wc * xs[i];
#pragma unroll
      for (int j = 0; j < DD; ++j) P[i * DD + j] += t * sh[j];
    }
  }
  float m[DD];
#pragma unroll
  for (int k = 0; k < DD; ++k) m[k] = 0.f;
#pragma unroll
  for (int i = 0; i < DD; ++i) {
#pragma unroll
    for (int j = 0; j < DD; ++j) {
      float p = P[i * DD + j];
#pragma unroll
      for (int k = 0; k < DD; ++k) m[k] += p * CG[i * 81 + j * DD + k];
    }
  }
#pragma unroll
  for (int k = 0; k < DD; ++k) m[k] += __shfl_xor(m[k], 32);
  if (h == 0) {
    float* mp = mpre + (size_t)wid * CD + c;
#pragma unroll
    for (int k = 0; k < DD; ++k) mp[k * 32] = m[k];
  }
}

// ---------------- fused output: m_i (out1) + self-connection (out2) ----------------
// 288 threads: thread (q,g). m_i passes through LDS, no global round-trip.
__global__ __launch_bounds__(288) void k_out(
    const float* __restrict__ attrs, const float* __restrict__ Wlin,
    const float* __restrict__ Wsc,
    float* __restrict__ out1, float* __restrict__ out2, int N) {
  __shared__ float smp[CD];    // mpre [d][c]
  __shared__ float smt[CD];    // m_i  [d][c]
  __shared__ float sres1[CD];  // out1 bounce [c][d]
  __shared__ float sres2[CD];  // out2 bounce [c][d]
  int t = threadIdx.x;
  int g = t >> 5, q = t & 31;
  int l0 = blk_of(g);
  float wl[CC];
#pragma unroll
  for (int c = 0; c < CC; ++c) wl[c] = Wlin[l0 * 1024 + c * 32 + q];
  float ws0[CC], ws1[CC], ws2[CC], ws3[CC];
#pragma unroll
  for (int c = 0; c < CC; ++c) {
    ws0[c] = Wsc[0 * 3072 + l0 * 1024 + c * 32 + q];
    ws1[c] = Wsc[1 * 3072 + l0 * 1024 + c * 32 + q];
    ws2[c] = Wsc[2 * 3072 + l0 * 1024 + c * 32 + q];
    ws3[c] = Wsc[3 * 3072 + l0 * 1024 + c * 32 + q];
  }
  for (int n = blockIdx.x; n < N; n += gridDim.x) {
    __syncthreads();                       // prev-iter LDS reads done
    smp[t] = out2[(size_t)n * CD + t];     // mpre, coalesced
    float a0 = attrs[n * 4 + 0], a1 = attrs[n * 4 + 1];
    float a2 = attrs[n * 4 + 2], a3 = attrs[n * 4 + 3];
    __syncthreads();
    // einsum1: m_i[q][g] = (1/16) sum_c mpre[g][c]*Wlin[l0][c][q]
    {
      const float4* rowp = (const float4*)(smp + g * 32);
      float b0 = 0.f, b1 = 0.f;
#pragma unroll
      for (int c4 = 0; c4 < 8; ++c4) {
        float4 b = rowp[c4];
        b0 += b.x * wl[c4 * 4 + 0] + b.y * wl[c4 * 4 + 1];
        b1 += b.z * wl[c4 * 4 + 2] + b.w * wl[c4 * 4 + 3];
      }
      float v = (b0 + b1) * (1.0f / 16.0f);
      smt[t] = v;                          // m_i [d][c] for einsum2
      sres1[q * DD + g] = v;               // ref layout bounce (9 coprime 32)
    }
    __syncthreads();
    // einsum2: scs[q][g] = sum_z a_z sum_c m_i[g][c]*Wsc[z][l0][c][q]
    {
      const float4* rowp = (const float4*)(smt + g * 32);
      float z0 = 0.f, z1 = 0.f, z2 = 0.f, z3 = 0.f;
#pragma unroll
      for (int c4 = 0; c4 < 8; ++c4) {
        float4 b = rowp[c4];
#pragma unroll
        for (int j = 0; j < 4; ++j) {
          float bv = (j == 0) ? b.x : (j == 1) ? b.y : (j == 2) ? b.z : b.w;
          int c = c4 * 4 + j;
          z0 += bv * ws0[c];
          z1 += bv * ws1[c];
          z2 += bv * ws2[c];
          z3 += bv * ws3[c];
        }
      }
      sres2[q * DD + g] = a0 * z0 + a1 * z1 + a2 * z2 + a3 * z3;
    }
    __syncthreads();
    if (t < 72) {
      float4 o1 = ((const float4*)sres1)[t];
      float4 o2 = ((const float4*)sres2)[t];
      ((float4*)(out1 + (size_t)n * CD))[t] = o1;
      ((float4*)(out2 + (size_t)n * CD))[t] = o2;
    }
  }
}

extern "C" void kernel_launch(void* const* d_in, const int* in_sizes, int n_in,
                              void* d_out, int out_size, void* d_ws, size_t ws_size,
                              hipStream_t stream) {
  const float* nf    = (const float*)d_in[0];
  const float* attrs = (const float*)d_in[1];
  const float* ef    = (const float*)d_in[2];
  const float* esh   = (const float*)d_in[3];
  const float* cutv  = (const float*)d_in[4];
  const float* Wup   = (const float*)d_in[5];
  const float* W1    = (const float*)d_in[6];
  const float* W2    = (const float*)d_in[7];
  const float* W3    = (const float*)d_in[8];
  const float* Wlin  = (const float*)d_in[9];
  const float* Wsc   = (const float*)d_in[10];
  const float* CG    = (const float*)d_in[11];
  const int* esrc    = (const int*)d_in[12];
  const int* edst    = (const int*)d_in[13];
  int N = in_sizes[0] / CD;
  int E = in_sizes[12];
  float* out1 = (float*)d_out;
  float* out2 = out1 + (size_t)N * CD;   // doubles as the m_pre accumulator

  float* x    = (float*)d_ws;                      // N*288 f32
  float* w    = x + (size_t)N * CD;                // E*32 f32
  int* deg    = (int*)(w + (size_t)E * CC);        // N
  int* offs   = deg + N;                           // N+1
  int* cursor = offs + N + 1;                      // N
  int* eidx   = cursor + N;                        // E
  float* W2T  = (float*)(eidx + E);                // 4096 f32

  k_zero<<<(N + 255) / 256, 256, 0, stream>>>((float*)deg, N);
  k_hist<<<(E + 255) / 256, 256, 0, stream>>>(edst, deg, E);
  k_scan<<<1, 1024, 0, stream>>>(deg, offs, cursor, N);
  k_scatter<<<(E + 255) / 256, 256, 0, stream>>>(edst, cursor, eidx, E);
  k_w2t<<<16, 256, 0, stream>>>(W2, W2T);
  k_linear_up<<<2048, 288, 0, stream>>>(nf, Wup, x, N);
  k_mlp<<<(E + 255) / 256, 256, 0, stream>>>(ef, cutv, W1, W2T, W3, w, E);
  k_gather<<<(N + 3) / 4, 256, 0, stream>>>(x, w, esh, CG, offs, eidx, esrc, out2, N);
  k_out<<<2048, 288, 0, stream>>>(attrs, Wlin, Wsc, out1, out2, N);
}